// Round 9
// baseline (68.760 us; speedup 1.0000x reference)
//
#include <hip/hip_runtime.h>
#include <hip/hip_fp16.h>
#include <math.h>

#define B_ 16
#define C_ 4
#define M_ 2048

typedef short bf16x8 __attribute__((ext_vector_type(8)));
typedef float f32x4 __attribute__((ext_vector_type(4)));

__device__ inline unsigned short f2bf(float f) {
  union { float f; unsigned u; } v; v.f = f;
  unsigned r = v.u + 0x7fffu + ((v.u >> 16) & 1u);
  return (unsigned short)(r >> 16);
}

// Static-index helpers: NO address-taken local arrays.
__device__ inline bf16x8 pack2(float4 a, float4 b) {
  bf16x8 r;
  r[0] = (short)f2bf(a.x); r[1] = (short)f2bf(a.y);
  r[2] = (short)f2bf(a.z); r[3] = (short)f2bf(a.w);
  r[4] = (short)f2bf(b.x); r[5] = (short)f2bf(b.y);
  r[6] = (short)f2bf(b.z); r[7] = (short)f2bf(b.w);
  return r;
}
__device__ inline float4 neg4(float4 a) { return make_float4(-a.x, -a.y, -a.z, -a.w); }
__device__ inline float4 sel4(int c, float4 a, float4 b) {
  return make_float4(c ? a.x : b.x, c ? a.y : b.y, c ? a.z : b.z, c ? a.w : b.w);
}

// Round-9: register-pressure elimination. Evidence chain: R4 measured 25/40 MB
// kernel FETCH/WRITE (scratch spill) at bfrag[8][4]; R6 (bfrag[4][4]) -16 us;
// R8 (lean epilogue) -5 us; occupancy changes: zero effect. Main-loop live set
// was still ~130 regs vs the allocator's hard 128 target -> residual spill.
// Fix: split n FOUR ways: 1024-thread blocks, 16 waves = (c, g in 0..3),
// bfrag[2][4] = 32 VGPRs/wave. Live set ~90 regs -> fits with slack, zero
// spill. Same MFMA/twiddle totals; 4 waves/SIMD; swapped-MFMA in-lane epilogue
// (R8) unchanged except the quad-butterfly now feeds 4 g-partials.
__global__ __launch_bounds__(1024) void nufft_kernel(const float* __restrict__ xr,
                                                     const float* __restrict__ xi,
                                                     const float* __restrict__ traj,
                                                     float* __restrict__ out) {
  const int b = blockIdx.x >> 4;
  const int m0 = (blockIdx.x & 15) * 128;
  const int tid = threadIdx.x;
  const int lane = tid & 63;
  const int wave = tid >> 6;
  const int c = wave & 3;
  const int g = wave >> 2;         // i-quarter this wave owns (0..3)
  const int col = lane & 15;
  const int quad = lane >> 4;

  __shared__ __align__(16) unsigned short ExS[128][136];  // [m][k] bf16 twiddles
  __shared__ __align__(16) float2 ypart[4][4][128];       // [g][c][m] partials

  // ---- B' fragments for this wave's i-quarter, built straight from xr/xi.
  // bfrag[nt][ks] = B'[c*128 + (g*2+nt)*16 + col][ks*32 + quad*8 .. +8]
  //   ri = col&1, i = g*16 + nt*8 + col/2; ks0/1: k<64, ks2/3: k>=64.
  bf16x8 bfrag[2][4];
  {
    const int ri = col & 1;
    const float* rb = xr + (size_t)((b * 4 + c) * 64) * 64;
    const float* ib = xi + (size_t)((b * 4 + c) * 64) * 64;
    const int ja = quad * 8;
    const int jb = 32 + quad * 8;
#pragma unroll
    for (int nt = 0; nt < 2; ++nt) {
      const int i = g * 16 + nt * 8 + (col >> 1);
      const float* rrow = rb + i * 64;
      const float* irow = ib + i * 64;
      const float4 r0 = *(const float4*)(rrow + ja);
      const float4 r1 = *(const float4*)(rrow + ja + 4);
      const float4 r2 = *(const float4*)(rrow + jb);
      const float4 r3 = *(const float4*)(rrow + jb + 4);
      const float4 i0 = *(const float4*)(irow + ja);
      const float4 i1 = *(const float4*)(irow + ja + 4);
      const float4 i2 = *(const float4*)(irow + jb);
      const float4 i3 = *(const float4*)(irow + jb + 4);
      // k<64: ri? xi : xr      k>=64: ri? xr : -xi
      bfrag[nt][0] = pack2(sel4(ri, i0, r0), sel4(ri, i1, r1));
      bfrag[nt][1] = pack2(sel4(ri, i2, r2), sel4(ri, i3, r3));
      bfrag[nt][2] = pack2(sel4(ri, r0, neg4(i0)), sel4(ri, r1, neg4(i1)));
      bfrag[nt][3] = pack2(sel4(ri, r2, neg4(i2)), sel4(ri, r3, neg4(i3)));
    }
  }

  // ---- Ex twiddle generation into LDS (verified recurrence convention).
  // Ex[m][j] = exp(-i*kx*(j-32)); re at k=j, im at k=64+j.
  // 1024 threads, 128 rows: 8 threads/row, 8-step segments.
  {
    const int mh = tid >> 3;         // 0..127
    const int j0 = (tid & 7) * 8;    // 8-step segment
    const float kx = traj[((size_t)b * M_ + m0 + mh) * 2 + 1];
    float sa, ca, su, cu;
    __sincosf(kx * (float)(j0 - 32), &sa, &ca);
    float vr = ca, vi = -sa;
    __sincosf(kx, &su, &cu);
    const float ur = cu, ui = -su;
#pragma unroll
    for (int s = 0; s < 8; ++s) {
      ExS[mh][j0 + s] = f2bf(vr);
      ExS[mh][64 + j0 + s] = f2bf(vi);
      const float nvr = fmaf(vr, ur, -(vi * ui));
      const float nvi = fmaf(vr, ui, vi * ur);
      vr = nvr; vi = nvi;
    }
  }
  __syncthreads();

#pragma unroll 1
  for (int s = 0; s < 8; ++s) {
    // ky for this lane's m = m0 + s*16 + col (L1-hot: twiddle phase touched it)
    const float ky = traj[((size_t)b * M_ + m0 + s * 16 + col) * 2 + 0];

    // Ex fragments from LDS (B-operand of the swapped MFMA)
    bf16x8 af[4];
#pragma unroll
    for (int ks = 0; ks < 4; ++ks)
      af[ks] = *(const bf16x8*)(&ExS[s * 16 + col][ks * 32 + quad * 8]);

    f32x4 acc[2];
#pragma unroll
    for (int nt = 0; nt < 2; ++nt) acc[nt] = (f32x4){0.f, 0.f, 0.f, 0.f};

    // SWAPPED operands: D[row = n-within-16][col = m-within-16]
    // acc[nt][r] = P'[n = c*128 + (g*2+nt)*16 + quad*4 + r][m = m0 + s*16 + col]
#pragma unroll
    for (int ks = 0; ks < 4; ++ks)
#pragma unroll
      for (int nt = 0; nt < 2; ++nt)
        acc[nt] = __builtin_amdgcn_mfma_f32_16x16x32_bf16(bfrag[nt][ks], af[ks], acc[nt], 0, 0, 0);

    // ---- In-lane epilogue: y[m] += sum_n Ey-coeff(n) * P'[n][m].
    // n parity: r&1 (Pr at even r, Pi at odd r); i = g*16 + nt*8 + quad*2 + (r>>1).
    // Ey(i) = exp(-i*ky*(i-32)) = (cos, -sin); rotation chain:
    //   base at i0 = g*16 + quad*2; +1 via (cu,-su); nt-step +8 via (c8,-s8).
    float su, cu, s8, c8, sb, cb;
    __sincosf(ky, &su, &cu);
    __sincosf(8.0f * ky, &s8, &c8);
    __sincosf(ky * (float)(g * 16 + quad * 2 - 32), &sb, &cb);
    float er = cb, ei = -sb;
    float yr = 0.f, yi = 0.f;
#pragma unroll
    for (int nt = 0; nt < 2; ++nt) {
      // e1 = e * (cu, -su)
      const float er1 = fmaf(er, cu, ei * su);
      const float ei1 = fmaf(ei, cu, -(er * su));
      yr = fmaf(er, acc[nt][0], fmaf(-ei, acc[nt][1], yr));
      yi = fmaf(ei, acc[nt][0], fmaf(er, acc[nt][1], yi));
      yr = fmaf(er1, acc[nt][2], fmaf(-ei1, acc[nt][3], yr));
      yi = fmaf(ei1, acc[nt][2], fmaf(er1, acc[nt][3], yi));
      // advance base by 8: e *= (c8, -s8)
      const float ern = fmaf(er, c8, ei * s8);
      const float ein = fmaf(ei, c8, -(er * s8));
      er = ern; ei = ein;
    }

    // Reduce over quad (lanes col, col+16, col+32, col+48): 2-stage butterfly.
    yr += __shfl_xor(yr, 16, 64);
    yr += __shfl_xor(yr, 32, 64);
    yi += __shfl_xor(yi, 16, 64);
    yi += __shfl_xor(yi, 32, 64);

    // Park this wave's g-quarter partial (disjoint per (g,c); no barrier needed).
    if (quad == 0) ypart[g][c][s * 16 + col] = make_float2(yr, yi);
  }

  __syncthreads();

  // Final cross-g reduction + coalesced float2 store. tid<512 -> (c, m_local).
  if (tid < 512) {
    const int cc = tid >> 7;        // 0..3
    const int m = tid & 127;        // 0..127
    const float2 a0 = ypart[0][cc][m];
    const float2 a1 = ypart[1][cc][m];
    const float2 a2 = ypart[2][cc][m];
    const float2 a3 = ypart[3][cc][m];
    float2 v;
    v.x = (a0.x + a1.x) + (a2.x + a3.x);
    v.y = (a0.y + a1.y) + (a2.y + a3.y);
    *(float2*)&out[((size_t)(b * 4 + cc) * M_ + m0 + m) * 2] = v;
  }
}

extern "C" void kernel_launch(void* const* d_in, const int* in_sizes, int n_in,
                              void* d_out, int out_size, void* d_ws, size_t ws_size,
                              hipStream_t stream) {
  const float* xr = (const float*)d_in[0];
  const float* xi = (const float*)d_in[1];
  const float* traj = (const float*)d_in[2];
  float* out = (float*)d_out;
  (void)d_ws; (void)ws_size;  // workspace unused (the 256 MiB poison fill is unconditional anyway)

  nufft_kernel<<<B_ * 16, 1024, 0, stream>>>(xr, xi, traj, out);
}